// Round 2
// baseline (1131.566 us; speedup 1.0000x reference)
//
#include <hip/hip_runtime.h>
#include <math.h>

// ---------------------------------------------------------------------------
// GraphSAGE 3-layer forward. N=100000, E=1200000, F: 64 -> 64 -> 32 -> 10.
// Strategy: build CSR (dst-sorted adjacency) once per call, then one fused
// kernel per layer: wave-per-node pull aggregation + shuffle-broadcast linear
// (weights in LDS) + L2 normalize + activation.
// NOTE: harness delivers integer inputs as int32 (edge_index int64 -> int*).
// ---------------------------------------------------------------------------

#define SCAN_BLOCK 1024

__global__ void degree_kernel(const int* __restrict__ ei, int* __restrict__ deg,
                              int E) {
    int e = blockIdx.x * blockDim.x + threadIdx.x;
    if (e < E) {
        int d = ei[E + e];   // dst row of edge_index
        atomicAdd(&deg[d], 1);
    }
}

// Single-block exclusive scan over deg[0..n) -> rowptr[0..n], also copy to cursor.
__global__ void scan_kernel(const int* __restrict__ deg, int* __restrict__ rowptr,
                            int* __restrict__ cursor, int n) {
    __shared__ int buf[SCAN_BLOCK];
    __shared__ int carry_s;
    if (threadIdx.x == 0) carry_s = 0;
    __syncthreads();
    for (int base = 0; base < n; base += SCAN_BLOCK) {
        int i = base + (int)threadIdx.x;
        int v = (i < n) ? deg[i] : 0;
        buf[threadIdx.x] = v;
        __syncthreads();
        for (int off = 1; off < SCAN_BLOCK; off <<= 1) {
            int t = (threadIdx.x >= (unsigned)off) ? buf[threadIdx.x - off] : 0;
            __syncthreads();
            buf[threadIdx.x] += t;
            __syncthreads();
        }
        int incl = buf[threadIdx.x];
        int excl = incl - v + carry_s;
        if (i < n) { rowptr[i] = excl; cursor[i] = excl; }
        __syncthreads();
        if (threadIdx.x == SCAN_BLOCK - 1) carry_s += incl;
        __syncthreads();
    }
    if (threadIdx.x == 0) rowptr[n] = carry_s;
}

__global__ void build_csr_kernel(const int* __restrict__ ei, int* __restrict__ cursor,
                                 int* __restrict__ col, int E) {
    int e = blockIdx.x * blockDim.x + threadIdx.x;
    if (e < E) {
        int s = ei[e];       // src row
        int d = ei[E + e];   // dst row
        int pos = atomicAdd(&cursor[d], 1);
        col[pos] = s;
    }
}

// ACT: 0 = none, 1 = relu, 2 = log_softmax
template <int F_IN, int F_OUT, int ACT>
__global__ __launch_bounds__(256) void sage_layer_kernel(
    const float* __restrict__ hin, const int* __restrict__ rowptr,
    const int* __restrict__ col, const float* __restrict__ Wl,
    const float* __restrict__ Wr, const float* __restrict__ b,
    float* __restrict__ hout, int n) {
    __shared__ float sWl[F_IN * F_OUT];
    __shared__ float sWr[F_IN * F_OUT];
    __shared__ float sb[F_OUT];
    for (int i = threadIdx.x; i < F_IN * F_OUT; i += blockDim.x) {
        sWl[i] = Wl[i];
        sWr[i] = Wr[i];
    }
    if (threadIdx.x < F_OUT) sb[threadIdx.x] = b[threadIdx.x];
    __syncthreads();

    const int wave = threadIdx.x >> 6;
    const int lane = threadIdx.x & 63;
    const int node = blockIdx.x * 4 + wave;
    if (node >= n) return;

    const int beg = rowptr[node];
    const int end = rowptr[node + 1];
    const int deg = end - beg;

    // ---- pull-aggregate: lane handles feature f (F_IN=32: 2 nbrs in parallel)
    constexpr int NSUB = 64 / F_IN;
    const int f = lane % F_IN;
    const int sub = lane / F_IN;
    float sum = 0.f;
    for (int e = beg + sub; e < end; e += NSUB) {
        int nbr = col[e];
        sum += hin[(size_t)nbr * F_IN + f];
    }
    if constexpr (NSUB == 2) sum += __shfl_xor(sum, 32);
    const float inv = (deg > 0) ? (1.f / (float)deg) : 0.f;
    const float agg = sum * inv;  // lanes sharing f hold identical value

    const float xi = (lane < F_IN) ? hin[(size_t)node * F_IN + lane] : 0.f;

    // ---- linear: lane j holds out[j] = b[j] + sum_k agg[k]*Wl[k][j] + x[k]*Wr[k][j]
    float acc = (lane < F_OUT) ? sb[lane] : 0.f;
#pragma unroll
    for (int k = 0; k < F_IN; ++k) {
        float a_k = __shfl(agg, k);
        float x_k = __shfl(xi, k);
        if (lane < F_OUT) acc += a_k * sWl[k * F_OUT + lane] + x_k * sWr[k * F_OUT + lane];
    }

    // ---- L2 normalize over lanes < F_OUT
    float v = (lane < F_OUT) ? acc * acc : 0.f;
#pragma unroll
    for (int off = 32; off; off >>= 1) v += __shfl_xor(v, off);
    const float scale = 1.f / fmaxf(sqrtf(v), 1e-12f);
    float o = acc * scale;

    if constexpr (ACT == 1) {
        o = fmaxf(o, 0.f);
    } else if constexpr (ACT == 2) {
        float m = (lane < F_OUT) ? o : -1e30f;
#pragma unroll
        for (int off = 32; off; off >>= 1) m = fmaxf(m, __shfl_xor(m, off));
        float ex = (lane < F_OUT) ? expf(o - m) : 0.f;
        float s = ex;
#pragma unroll
        for (int off = 32; off; off >>= 1) s += __shfl_xor(s, off);
        o = o - m - logf(s);
    }

    if (lane < F_OUT) hout[(size_t)node * F_OUT + lane] = o;
}

extern "C" void kernel_launch(void* const* d_in, const int* in_sizes, int n_in,
                              void* d_out, int out_size, void* d_ws, size_t ws_size,
                              hipStream_t stream) {
    const float* x   = (const float*)d_in[0];
    const int*   ei  = (const int*)d_in[1];     // int64 in ref, int32 on device
    const float* W1l = (const float*)d_in[2];
    const float* W1r = (const float*)d_in[3];
    const float* b1  = (const float*)d_in[4];
    const float* W2l = (const float*)d_in[5];
    const float* W2r = (const float*)d_in[6];
    const float* b2  = (const float*)d_in[7];
    const float* W3l = (const float*)d_in[8];
    const float* W3r = (const float*)d_in[9];
    const float* b3  = (const float*)d_in[10];
    float*       out = (float*)d_out;

    const int N = in_sizes[0] / 64;
    const int E = in_sizes[1] / 2;

    // workspace layout (16B aligned)
    auto align16 = [](size_t v) { return (v + 15) & ~(size_t)15; };
    char* ws = (char*)d_ws;
    size_t off = 0;
    int* deg    = (int*)(ws + off); off = align16(off + (size_t)N * 4);
    int* rowptr = (int*)(ws + off); off = align16(off + (size_t)(N + 1) * 4);
    int* cursor = (int*)(ws + off); off = align16(off + (size_t)N * 4);
    int* colidx = (int*)(ws + off); off = align16(off + (size_t)E * 4);
    float* h1   = (float*)(ws + off); off = align16(off + (size_t)N * 64 * 4);
    float* h2   = (float*)(ws + off); off = align16(off + (size_t)N * 32 * 4);
    (void)ws_size; (void)n_in; (void)out_size;

    // ---- CSR build
    hipMemsetAsync(deg, 0, (size_t)N * 4, stream);
    degree_kernel<<<(E + 255) / 256, 256, 0, stream>>>(ei, deg, E);
    scan_kernel<<<1, SCAN_BLOCK, 0, stream>>>(deg, rowptr, cursor, N);
    build_csr_kernel<<<(E + 255) / 256, 256, 0, stream>>>(ei, cursor, colidx, E);

    // ---- layers
    const int blocks = (N + 3) / 4;  // 4 waves (nodes) per 256-thread block
    sage_layer_kernel<64, 64, 1><<<blocks, 256, 0, stream>>>(x,  rowptr, colidx, W1l, W1r, b1, h1, N);
    sage_layer_kernel<64, 32, 1><<<blocks, 256, 0, stream>>>(h1, rowptr, colidx, W2l, W2r, b2, h2, N);
    sage_layer_kernel<32, 10, 2><<<blocks, 256, 0, stream>>>(h2, rowptr, colidx, W3l, W3r, b3, out, N);
}

// Round 3
// 653.746 us; speedup vs baseline: 1.7309x; 1.7309x over previous
//
#include <hip/hip_runtime.h>
#include <math.h>

// ---------------------------------------------------------------------------
// GraphSAGE 3-layer forward, transform-then-aggregate formulation.
// mean(x[src]) @ Wl == mean(x[src] @ Wl)  (mean commutes with linear), so:
//   K1: y1l = x@W1l,  y1r = x@W1r + b1               (dense, coalesced)
//   K2: h1 = relu(norm(gather_mean(y1l) + y1r)); emit y2l=h1@W2l, y2r=h1@W2r+b2
//   K3: h2 = relu(norm(gather_mean(y2l) + y2r)); emit y3l,y3r (width 10 pad 16)
//   K4: o  = norm(gather_mean(y3l) + y3r); log_softmax -> out
// Gather uses float4 lanes: F=64 -> 4 nbrs in flight/wave, F=32 -> 8, F=16 -> 16.
// CSR built per call; rowptr via decoupled block scan (atomic block base —
// bucket placement nondeterministic, numerically irrelevant).
// ---------------------------------------------------------------------------

__global__ void degree_kernel(const int* __restrict__ ei, int* __restrict__ deg, int E) {
    int e = blockIdx.x * blockDim.x + threadIdx.x;
    if (e < E) atomicAdd(&deg[ei[E + e]], 1);
}

__global__ __launch_bounds__(1024) void scan_block_kernel(
        const int* __restrict__ deg, int* __restrict__ rowptr,
        int* __restrict__ cursor, int* __restrict__ counter, int n) {
    __shared__ int buf[1024];
    __shared__ int base_s;
    const int i = blockIdx.x * 1024 + threadIdx.x;
    const int v = (i < n) ? deg[i] : 0;
    buf[threadIdx.x] = v;
    __syncthreads();
    for (int off = 1; off < 1024; off <<= 1) {
        int t = (threadIdx.x >= (unsigned)off) ? buf[threadIdx.x - off] : 0;
        __syncthreads();
        buf[threadIdx.x] += t;
        __syncthreads();
    }
    if (threadIdx.x == 0) base_s = atomicAdd(counter, buf[1023]);
    __syncthreads();
    const int excl = buf[threadIdx.x] - v + base_s;
    if (i < n) { rowptr[i] = excl; cursor[i] = excl; }
}

__global__ void build_csr_kernel(const int* __restrict__ ei, int* __restrict__ cursor,
                                 int* __restrict__ col, int E) {
    int e = blockIdx.x * blockDim.x + threadIdx.x;
    if (e < E) {
        int pos = atomicAdd(&cursor[ei[E + e]], 1);
        col[pos] = ei[e];
    }
}

// K1: dense per-node transform of x (64 -> 64 both matrices).
__global__ __launch_bounds__(256) void transform1_kernel(
        const float* __restrict__ x, const float* __restrict__ Wl,
        const float* __restrict__ Wr, const float* __restrict__ b,
        float* __restrict__ yl, float* __restrict__ yr, int n) {
    __shared__ float sWl[64 * 64];
    __shared__ float sWr[64 * 64];
    __shared__ float sb[64];
    for (int i = threadIdx.x; i < 64 * 64; i += 256) { sWl[i] = Wl[i]; sWr[i] = Wr[i]; }
    if (threadIdx.x < 64) sb[threadIdx.x] = b[threadIdx.x];
    __syncthreads();
    const int lane = threadIdx.x & 63;
    const int node = blockIdx.x * 4 + (threadIdx.x >> 6);
    if (node >= n) return;
    const float xi = x[(size_t)node * 64 + lane];
    float accl = 0.f, accr = sb[lane];
#pragma unroll
    for (int k = 0; k < 64; ++k) {
        const float xk = __shfl(xi, k);
        accl += xk * sWl[k * 64 + lane];
        accr += xk * sWr[k * 64 + lane];
    }
    yl[(size_t)node * 64 + lane] = accl;
    yr[(size_t)node * 64 + lane] = accr;
}

// K2/K3: gather(width F_IN, float4 lanes) + norm + relu + next-layer transform.
template <int F_IN, int F_OUT, int F_PAD>
__global__ __launch_bounds__(256) void gt_kernel(
        const float* __restrict__ yl_in, const float* __restrict__ yr_in,
        const int* __restrict__ rowptr, const int* __restrict__ deg_arr,
        const int* __restrict__ col,
        const float* __restrict__ Wl, const float* __restrict__ Wr,
        const float* __restrict__ b,
        float* __restrict__ yl_out, float* __restrict__ yr_out, int n) {
    __shared__ float sWl[F_IN * F_OUT];
    __shared__ float sWr[F_IN * F_OUT];
    __shared__ float sb[F_OUT];
    for (int i = threadIdx.x; i < F_IN * F_OUT; i += 256) { sWl[i] = Wl[i]; sWr[i] = Wr[i]; }
    if (threadIdx.x < F_OUT) sb[threadIdx.x] = b[threadIdx.x];
    __syncthreads();

    const int lane = threadIdx.x & 63;
    const int node = blockIdx.x * 4 + (threadIdx.x >> 6);
    if (node >= n) return;

    const int dg  = deg_arr[node];
    const int beg = rowptr[node];
    const int end = beg + dg;

    constexpr int NCH = F_IN / 4;       // float4 chunks per row
    const int ch  = lane % NCH;
    const int sub = lane / NCH;         // 64/NCH neighbors in flight
    float4 v = make_float4(0.f, 0.f, 0.f, 0.f);
    for (int e = beg + sub; e < end; e += 64 / NCH) {
        const int nbr = col[e];
        const float4 t = *(const float4*)(yl_in + (size_t)nbr * F_IN + ch * 4);
        v.x += t.x; v.y += t.y; v.z += t.z; v.w += t.w;
    }
#pragma unroll
    for (int off = NCH; off < 64; off <<= 1) {
        v.x += __shfl_xor(v.x, off);
        v.y += __shfl_xor(v.y, off);
        v.z += __shfl_xor(v.z, off);
        v.w += __shfl_xor(v.w, off);
    }
    const float inv = (dg > 0) ? 1.f / (float)dg : 0.f;
    // relayout float4-chunks -> lane-per-feature scalar
    const int srcl = lane >> 2;         // lane srcl holds chunk srcl (srcl < NCH)
    const float a0 = __shfl(v.x, srcl), a1 = __shfl(v.y, srcl),
                a2 = __shfl(v.z, srcl), a3 = __shfl(v.w, srcl);
    const float hv = (lane & 2) ? ((lane & 1) ? a3 : a2) : ((lane & 1) ? a1 : a0);
    const float o = (lane < F_IN) ? hv * inv + yr_in[(size_t)node * F_IN + lane] : 0.f;
    float s2 = o * o;
#pragma unroll
    for (int off = 1; off < 64; off <<= 1) s2 += __shfl_xor(s2, off);
    const float h = fmaxf(o * (1.f / fmaxf(sqrtf(s2), 1e-12f)), 0.f);  // norm + relu

    // next-layer transform
    float accl = 0.f, accr = (lane < F_OUT) ? sb[lane] : 0.f;
#pragma unroll
    for (int k = 0; k < F_IN; ++k) {
        const float hk = __shfl(h, k);
        if (lane < F_OUT) {
            accl += hk * sWl[k * F_OUT + lane];
            accr += hk * sWr[k * F_OUT + lane];
        }
    }
    if (lane < F_PAD) {
        yl_out[(size_t)node * F_PAD + lane] = (lane < F_OUT) ? accl : 0.f;
        yr_out[(size_t)node * F_PAD + lane] = (lane < F_OUT) ? accr : 0.f;
    }
}

// K4: gather width 16 (10 real), norm, log_softmax.
__global__ __launch_bounds__(256) void final_kernel(
        const float* __restrict__ yl_in, const float* __restrict__ yr_in,
        const int* __restrict__ rowptr, const int* __restrict__ deg_arr,
        const int* __restrict__ col, float* __restrict__ out, int n) {
    const int lane = threadIdx.x & 63;
    const int node = blockIdx.x * 4 + (threadIdx.x >> 6);
    if (node >= n) return;
    const int dg  = deg_arr[node];
    const int beg = rowptr[node];
    const int end = beg + dg;
    const int ch = lane & 3, sub = lane >> 2;   // 16 neighbors in flight
    float4 v = make_float4(0.f, 0.f, 0.f, 0.f);
    for (int e = beg + sub; e < end; e += 16) {
        const int nbr = col[e];
        const float4 t = *(const float4*)(yl_in + (size_t)nbr * 16 + ch * 4);
        v.x += t.x; v.y += t.y; v.z += t.z; v.w += t.w;
    }
#pragma unroll
    for (int off = 4; off < 64; off <<= 1) {
        v.x += __shfl_xor(v.x, off);
        v.y += __shfl_xor(v.y, off);
        v.z += __shfl_xor(v.z, off);
        v.w += __shfl_xor(v.w, off);
    }
    const float inv = (dg > 0) ? 1.f / (float)dg : 0.f;
    const int srcl = lane >> 2;
    const float a0 = __shfl(v.x, srcl), a1 = __shfl(v.y, srcl),
                a2 = __shfl(v.z, srcl), a3 = __shfl(v.w, srcl);
    const float hv = (lane & 2) ? ((lane & 1) ? a3 : a2) : ((lane & 1) ? a1 : a0);
    float o = (lane < 16) ? hv * inv + yr_in[(size_t)node * 16 + lane] : 0.f;
    float s2 = o * o;
#pragma unroll
    for (int off = 1; off < 64; off <<= 1) s2 += __shfl_xor(s2, off);
    o *= 1.f / fmaxf(sqrtf(s2), 1e-12f);
    // log_softmax over the 10 real outputs
    float m = (lane < 10) ? o : -INFINITY;
#pragma unroll
    for (int off = 1; off < 64; off <<= 1) m = fmaxf(m, __shfl_xor(m, off));
    float ex = (lane < 10) ? __expf(o - m) : 0.f;
    float s = ex;
#pragma unroll
    for (int off = 1; off < 64; off <<= 1) s += __shfl_xor(s, off);
    if (lane < 10) out[(size_t)node * 10 + lane] = o - m - logf(s);
}

extern "C" void kernel_launch(void* const* d_in, const int* in_sizes, int n_in,
                              void* d_out, int out_size, void* d_ws, size_t ws_size,
                              hipStream_t stream) {
    const float* x   = (const float*)d_in[0];
    const int*   ei  = (const int*)d_in[1];     // int64 in ref -> int32 on device
    const float* W1l = (const float*)d_in[2];
    const float* W1r = (const float*)d_in[3];
    const float* b1  = (const float*)d_in[4];
    const float* W2l = (const float*)d_in[5];
    const float* W2r = (const float*)d_in[6];
    const float* b2  = (const float*)d_in[7];
    const float* W3l = (const float*)d_in[8];
    const float* W3r = (const float*)d_in[9];
    const float* b3  = (const float*)d_in[10];
    float*       out = (float*)d_out;

    const int N = in_sizes[0] / 64;
    const int E = in_sizes[1] / 2;

    auto align16 = [](size_t v) { return (v + 15) & ~(size_t)15; };
    char* ws = (char*)d_ws;
    size_t off = 0;
    int* deg     = (int*)(ws + off); off = align16(off + (size_t)(N + 1) * 4);
    int* counter = deg + N;          // zeroed together with deg
    int* rowptr  = (int*)(ws + off); off = align16(off + (size_t)N * 4);
    int* cursor  = (int*)(ws + off); off = align16(off + (size_t)N * 4);
    int* colidx  = (int*)(ws + off); off = align16(off + (size_t)E * 4);
    float* y1l = (float*)(ws + off); off = align16(off + (size_t)N * 64 * 4);
    float* y1r = (float*)(ws + off); off = align16(off + (size_t)N * 64 * 4);
    float* y2l = (float*)(ws + off); off = align16(off + (size_t)N * 32 * 4);
    float* y2r = (float*)(ws + off); off = align16(off + (size_t)N * 32 * 4);
    float* y3l = (float*)(ws + off); off = align16(off + (size_t)N * 16 * 4);
    float* y3r = (float*)(ws + off); off = align16(off + (size_t)N * 16 * 4);
    (void)ws_size; (void)n_in; (void)out_size;

    // ---- CSR build
    hipMemsetAsync(deg, 0, (size_t)(N + 1) * 4, stream);
    degree_kernel<<<(E + 255) / 256, 256, 0, stream>>>(ei, deg, E);
    scan_block_kernel<<<(N + 1023) / 1024, 1024, 0, stream>>>(deg, rowptr, cursor, counter, N);
    build_csr_kernel<<<(E + 255) / 256, 256, 0, stream>>>(ei, cursor, colidx, E);

    // ---- layers
    const int blocks4 = (N + 3) / 4;
    transform1_kernel<<<blocks4, 256, 0, stream>>>(x, W1l, W1r, b1, y1l, y1r, N);
    gt_kernel<64, 32, 32><<<blocks4, 256, 0, stream>>>(y1l, y1r, rowptr, deg, colidx,
                                                       W2l, W2r, b2, y2l, y2r, N);
    gt_kernel<32, 10, 16><<<blocks4, 256, 0, stream>>>(y2l, y2r, rowptr, deg, colidx,
                                                       W3l, W3r, b3, y3l, y3r, N);
    final_kernel<<<blocks4, 256, 0, stream>>>(y3l, y3r, rowptr, deg, colidx, out, N);
}